// Round 14
// baseline (118.250 us; speedup 1.0000x reference)
//
#include <hip/hip_runtime.h>
#include <math.h>

#define BB 32
#define LL 1024
#define DIMM 64
#define DINN 256
#define NHEADS 4
#define DSTATE 16
#define DINPROJ 548
#define EPSF 1e-5f
#define NCH 16    // chunks per sequence
#define CS 64     // chunk size

typedef __attribute__((ext_vector_type(8))) short bf16x8;
typedef __attribute__((ext_vector_type(4))) float f32x4;

__device__ inline ushort f2bf(float f) {
    union { float f; unsigned u; } v; v.f = f;
    unsigned r = (v.u + 0x7FFFu + ((v.u >> 16) & 1u)) >> 16;
    return (ushort)r;
}
__device__ inline float bf2f(ushort u) {
    union { float f; unsigned u; } v; v.u = ((unsigned)u) << 16; return v.f;
}
__device__ inline float fexp(float v) { return __expf(v); }
__device__ inline float fsilu(float v) {
    return v * __builtin_amdgcn_rcpf(1.f + __expf(-v));
}
__device__ inline bf16x8 pack8(float4 a, float4 b) {
    bf16x8 r; ushort* p = (ushort*)&r;
    p[0] = f2bf(a.x); p[1] = f2bf(a.y); p[2] = f2bf(a.z); p[3] = f2bf(a.w);
    p[4] = f2bf(b.x); p[5] = f2bf(b.y); p[6] = f2bf(b.z); p[7] = f2bf(b.w);
    return r;
}

// -- K1: M=64; RMSNorm + in_proj xBC (bf16 MFMA, fp32 weights inline-cvt) + dt --
// grid 512, block 256 = 4 waves
__global__ __launch_bounds__(256) void k1_mfma(
        const float* __restrict__ x, const float* __restrict__ Wfp,
        const float* __restrict__ bnw, const float* __restrict__ dt_bias,
        ushort* __restrict__ xbcbuf, float* __restrict__ dtbuf) {
    __shared__ __align__(16) union {
        struct { float u[64][68]; float wdt[4][68]; } a;   // 18.5 KB
        ushort ob[64][296];                                 // 37.9 KB (592B rows, 16B-mult)
    } s;
    __shared__ float rstd[64];
    const int t = threadIdx.x;
    const int m0 = blockIdx.x * 64;
    const int b = m0 >> 10;
    const int lbase = m0 & 1023;

    const float* xrow = x + (size_t)m0 * 64;
    #pragma unroll
    for (int i = 0; i < 4; ++i) {
        int idx = t + i * 256;
        float4 v = ((const float4*)xrow)[idx];
        *(float4*)&s.a.u[idx >> 4][(idx & 15) * 4] = v;
    }
    s.a.wdt[t >> 6][t & 63] = Wfp[(size_t)(544 + (t >> 6)) * 64 + (t & 63)] * bnw[t & 63];
    __syncthreads();
    {
        int row = t >> 2, part = t & 3;
        float ss = 0.f;
        #pragma unroll
        for (int j = 0; j < 16; ++j) { float v = s.a.u[row][part * 16 + j]; ss = fmaf(v, v, ss); }
        ss += __shfl_xor(ss, 1); ss += __shfl_xor(ss, 2);
        if (part == 0) rstd[row] = rsqrtf(ss * (1.f / 64.f) + EPSF);
    }
    __syncthreads();

    const int w = t >> 6, l = t & 63;
    const int a = l & 15, kb = (l >> 4) * 8;

    float4 bw[2][2];
    bw[0][0] = *(const float4*)&bnw[kb];
    bw[0][1] = *(const float4*)&bnw[kb + 4];
    bw[1][0] = *(const float4*)&bnw[32 + kb];
    bw[1][1] = *(const float4*)&bnw[32 + kb + 4];

    bf16x8 af[4][2];
    #pragma unroll
    for (int mt = 0; mt < 4; ++mt) {
        float rs = rstd[mt * 16 + a];
        #pragma unroll
        for (int kk = 0; kk < 2; ++kk) {
            float4 v0 = *(const float4*)&s.a.u[mt * 16 + a][kk * 32 + kb];
            float4 v1 = *(const float4*)&s.a.u[mt * 16 + a][kk * 32 + kb + 4];
            ushort* p = (ushort*)&af[mt][kk];
            p[0] = f2bf(v0.x * rs * bw[kk][0].x);
            p[1] = f2bf(v0.y * rs * bw[kk][0].y);
            p[2] = f2bf(v0.z * rs * bw[kk][0].z);
            p[3] = f2bf(v0.w * rs * bw[kk][0].w);
            p[4] = f2bf(v1.x * rs * bw[kk][1].x);
            p[5] = f2bf(v1.y * rs * bw[kk][1].y);
            p[6] = f2bf(v1.z * rs * bw[kk][1].z);
            p[7] = f2bf(v1.w * rs * bw[kk][1].w);
        }
    }

    // fp32 dt + softplus (all 256 threads: 64 rows x 4 heads)
    {
        int row = t >> 2, h = t & 3;
        const float* ur = s.a.u[row];
        const float* wr = s.a.wdt[h];
        float sd = 0.f;
        #pragma unroll
        for (int k4 = 0; k4 < 16; ++k4) {
            float4 uv = *(const float4*)&ur[k4 * 4];
            float4 wv = *(const float4*)&wr[k4 * 4];
            sd = fmaf(uv.x, wv.x, sd); sd = fmaf(uv.y, wv.y, sd);
            sd = fmaf(uv.z, wv.z, sd); sd = fmaf(uv.w, wv.w, sd);
        }
        sd = sd * rstd[row] + dt_bias[h];
        sd = fmaxf(sd, 0.f) + log1pf(expf(-fabsf(sd)));   // keep precise
        dtbuf[((size_t)(b * 4 + h)) * LL + lbase + row] = sd;
    }
    __syncthreads();   // u/wdt dead; ob may now be written

    // xBC columns: nt = 16..33, fp32 weights converted inline
    for (int nt = 16 + w; nt < 34; nt += 4) {
        const float* wrow = Wfp + (size_t)(nt * 16 + a) * 64 + kb;
        bf16x8 b0 = pack8(*(const float4*)&wrow[0],  *(const float4*)&wrow[4]);
        bf16x8 b1 = pack8(*(const float4*)&wrow[32], *(const float4*)&wrow[36]);
        #pragma unroll
        for (int mt = 0; mt < 4; ++mt) {
            f32x4 acc = {0.f, 0.f, 0.f, 0.f};
            acc = __builtin_amdgcn_mfma_f32_16x16x32_bf16(af[mt][0], b0, acc, 0, 0, 0);
            acc = __builtin_amdgcn_mfma_f32_16x16x32_bf16(af[mt][1], b1, acc, 0, 0, 0);
            int row0 = mt * 16 + (l >> 4) * 4;
            int col = nt * 16 + a - 256;
            #pragma unroll
            for (int r = 0; r < 4; ++r) s.ob[row0 + r][col] = f2bf(acc[r]);
        }
    }
    __syncthreads();

    for (int i = t; i < 2304; i += 256) {           // 64 rows x 36 chunks
        int row = i / 36, c8 = (i % 36) * 8;
        *(uint4*)&xbcbuf[(size_t)(m0 + row) * 288 + c8] = *(const uint4*)&s.ob[row][c8];
    }
}

// ---------------- K3a: SSD chunked scan via MFMA (bf16 in/out) ----------------
__global__ __launch_bounds__(256) void k3a_ssd(
        const ushort* __restrict__ xbcbuf, const float* __restrict__ dtbuf,
        const float* __restrict__ conv_w, const float* __restrict__ conv_b,
        const float* __restrict__ A_log, const float* __restrict__ Dp,
        ushort* __restrict__ y, float* __restrict__ h0buf,
        float* __restrict__ cdecbuf, ushort* __restrict__ Cpost) {
    const int bid = blockIdx.x;
    const int c = bid & 15, h = (bid >> 4) & 3, b = bid >> 6;
    const int t = threadIdx.x;

    __shared__ __align__(16) union {
        struct { ushort rawx[67][64]; ushort rawbc[67][32]; } st;
        struct { ushort Mb[64][72]; ushort BwT[16][72]; } ssd;
    } uu;
    __shared__ ushort XbT[64][72];
    __shared__ ushort Bb[64][40];
    __shared__ ushort Cb[64][40];
    __shared__ float dtt[64], laa[64], ww[64];

    const float A  = -expf(A_log[h]);
    const float Dh = Dp[h];
    const int l0 = c * CS;
    const ushort* xb = xbcbuf + (size_t)b * LL * 288;

    for (int i = t; i < 67 * 32; i += 256) {
        int r = i >> 5, cu = i & 31;
        int l = l0 - 3 + r;
        ((uint*)&uu.st.rawx[r][0])[cu] =
            (l >= 0) ? ((const uint*)(xb + (size_t)l * 288 + h * 64))[cu] : 0u;
    }
    for (int i = t; i < 67 * 16; i += 256) {
        int r = i >> 4, cu = i & 15;
        int l = l0 - 3 + r;
        ((uint*)&uu.st.rawbc[r][0])[cu] =
            (l >= 0) ? ((const uint*)(xb + (size_t)l * 288 + 256))[cu] : 0u;
    }
    for (int i = t; i < 512; i += 256) {
        int r = i >> 3, cc = i & 7;
        ((uint*)&Bb[r][16])[cc] = 0;
        ((uint*)&Cb[r][16])[cc] = 0;
    }
    if (t < 64) {
        float dv = dtbuf[((size_t)(b * 4 + h)) * LL + l0 + t];
        float run = dv * A;
        #pragma unroll
        for (int off = 1; off < 64; off <<= 1) {
            float o = __shfl_up(run, off, 64);
            if (t >= off) run += o;
        }
        dtt[t] = dv;
        laa[t] = run;
        cdecbuf[((size_t)(b * 4 + h)) * LL + l0 + t] = fexp(run);
        float laEnd = __shfl(run, 63, 64);
        ww[t] = dv * fexp(laEnd - run);
    }
    __syncthreads();

    {
        const int jx = t & 63;
        const int w0 = (t >> 6) * 16;
        const int cx = h * 64 + jx;
        const float4 cwx = *(const float4*)&conv_w[cx * 4];
        const float  cbx = conv_b[cx];
        float r0[19];
        #pragma unroll
        for (int k = 0; k < 19; ++k) r0[k] = bf2f(uu.st.rawx[w0 + k][jx]);
        ushort vv[16];
        #pragma unroll
        for (int k = 0; k < 16; ++k) {
            float v = cbx + r0[k] * cwx.x + r0[k + 1] * cwx.y
                          + r0[k + 2] * cwx.z + r0[k + 3] * cwx.w;
            vv[k] = f2bf(fsilu(v));
        }
        *(bf16x8*)&XbT[jx][w0]     = *(bf16x8*)&vv[0];
        *(bf16x8*)&XbT[jx][w0 + 8] = *(bf16x8*)&vv[8];

        const int jbc = t & 31, cbc = 256 + jbc;
        const float4 cwb = *(const float4*)&conv_w[cbc * 4];
        const float  cbb = conv_b[cbc];
        #pragma unroll
        for (int i = 0; i < 8; ++i) {
            int ss = (t >> 5) + i * 8;
            float v = cbb + bf2f(uu.st.rawbc[ss][jbc]) * cwb.x
                          + bf2f(uu.st.rawbc[ss + 1][jbc]) * cwb.y
                          + bf2f(uu.st.rawbc[ss + 2][jbc]) * cwb.z
                          + bf2f(uu.st.rawbc[ss + 3][jbc]) * cwb.w;
            v = fsilu(v);
            if (jbc < 16) Bb[ss][jbc] = f2bf(v);
            else {
                ushort bv = f2bf(v);
                Cb[ss][jbc - 16] = bv;
                Cpost[((size_t)b * LL + l0 + ss) * DSTATE + (jbc - 16)] = bv;
            }
        }
    }
    __syncthreads();

    const int w = t >> 6, l = t & 63;
    const int fr = l & 15, fq = l >> 4;

    f32x4 gacc[4];
    {
        bf16x8 ca = *(const bf16x8*)&Cb[w * 16 + fr][fq * 8];
        #pragma unroll
        for (int jt = 0; jt < 4; ++jt) {
            bf16x8 bb = *(const bf16x8*)&Bb[jt * 16 + fr][fq * 8];
            f32x4 z = {0.f, 0.f, 0.f, 0.f};
            gacc[jt] = __builtin_amdgcn_mfma_f32_16x16x32_bf16(ca, bb, z, 0, 0, 0);
        }
    }
    #pragma unroll
    for (int jt = 0; jt < 4; ++jt) {
        int j = jt * 16 + fr;
        float laj = laa[j], dtj = dtt[j];
        #pragma unroll
        for (int r = 0; r < 4; ++r) {
            int i = w * 16 + fq * 4 + r;
            float m = (j <= i) ? gacc[jt][r] * fexp(laa[i] - laj) * dtj : 0.f;
            uu.ssd.Mb[i][j] = f2bf(m);
        }
    }
    #pragma unroll
    for (int i2 = 0; i2 < 4; ++i2) {
        int idx = t + i2 * 256;
        int n = idx & 15, jj = idx >> 4;
        uu.ssd.BwT[n][jj] = f2bf(ww[jj] * bf2f(Bb[jj][n]));
    }

    {
        bf16x8 ma0 = *(const bf16x8*)&uu.ssd.Mb[w * 16 + fr][fq * 8];
        bf16x8 ma1 = *(const bf16x8*)&uu.ssd.Mb[w * 16 + fr][32 + fq * 8];
        #pragma unroll
        for (int pt = 0; pt < 4; ++pt) {
            bf16x8 xb0 = *(const bf16x8*)&XbT[pt * 16 + fr][fq * 8];
            bf16x8 xb1 = *(const bf16x8*)&XbT[pt * 16 + fr][32 + fq * 8];
            f32x4 acc = {0.f, 0.f, 0.f, 0.f};
            acc = __builtin_amdgcn_mfma_f32_16x16x32_bf16(ma0, xb0, acc, 0, 0, 0);
            acc = __builtin_amdgcn_mfma_f32_16x16x32_bf16(ma1, xb1, acc, 0, 0, 0);
            #pragma unroll
            for (int r = 0; r < 4; ++r) {
                int i = w * 16 + fq * 4 + r;
                int p = pt * 16 + fr;
                float xv = bf2f(XbT[p][i]);
                uu.ssd.Mb[i][p] = f2bf(acc[r] + Dh * xv);
            }
        }
    }
    __syncthreads();

    if (c < 15) {
        bf16x8 xa0 = *(const bf16x8*)&XbT[w * 16 + fr][fq * 8];
        bf16x8 xa1 = *(const bf16x8*)&XbT[w * 16 + fr][32 + fq * 8];
        bf16x8 bw0 = *(const bf16x8*)&uu.ssd.BwT[fr][fq * 8];
        bf16x8 bw1 = *(const bf16x8*)&uu.ssd.BwT[fr][32 + fq * 8];
        f32x4 acc = {0.f, 0.f, 0.f, 0.f};
        acc = __builtin_amdgcn_mfma_f32_16x16x32_bf16(xa0, bw0, acc, 0, 0, 0);
        acc = __builtin_amdgcn_mfma_f32_16x16x32_bf16(xa1, bw1, acc, 0, 0, 0);
        float* Sdst = h0buf + (((size_t)(b * 4 + h)) * NCH + (c + 1)) * 1024;
        #pragma unroll
        for (int r = 0; r < 4; ++r) {
            int p = w * 16 + fq * 4 + r;
            Sdst[p * 16 + fr] = acc[r];
        }
    }

    {
        ushort* ybase = y + ((size_t)b * LL + l0) * DINN + h * 64;
        #pragma unroll
        for (int ii = 0; ii < 2; ++ii) {
            int idx = t + ii * 256;
            int row = idx >> 3, c8 = (idx & 7) * 8;
            *(uint4*)&ybase[(size_t)row * DINN + c8] = *(const uint4*)&uu.ssd.Mb[row][c8];
        }
    }
}

// -- K4: inline chunk-scan (replaces k3b) + z recompute + gate + RMSNorm + out_proj --
// grid 512 = (b, chunk); block 256 = 4 waves
__global__ __launch_bounds__(256) void k4_out(
        const ushort* __restrict__ ybf, const float* __restrict__ ngw,
        const float* __restrict__ Wofp, const float* __restrict__ Wfp,
        const float* __restrict__ bnw, const float* __restrict__ x,
        const float* __restrict__ h0buf, const float* __restrict__ cdecbuf,
        const ushort* __restrict__ Cpost, float* __restrict__ out) {
    __shared__ __align__(16) union {
        float u[64][68];        // 17.4 KB (phase A)
        ushort zg[64][264];     // 33.8 KB (silu(z) then g)
    } s;
    __shared__ float Cs[64][16];
    __shared__ float cds[64][4];
    __shared__ float rstd[64];
    const int t = threadIdx.x;
    const int m0 = blockIdx.x * 64;
    const int b  = m0 >> 10;
    const int l0 = m0 & 1023;
    const int ck = l0 >> 6;
    const ushort* yb = ybf + (size_t)m0 * DINN;

    const int w = t >> 6, l = t & 63;
    const int ch4 = l * 4;
    const int hh  = ch4 >> 6;
    const int p0  = ch4 & 63;
    const int a = l & 15, kb = (l >> 4) * 8;
    const int j = l & 15;

    // stage x tile (64 x 64 fp32), C, cdec
    const float* xrow = x + (size_t)m0 * 64;
    #pragma unroll
    for (int i = 0; i < 4; ++i) {
        int idx = t + i * 256;
        float4 v = ((const float4*)xrow)[idx];
        *(float4*)&s.u[idx >> 4][(idx & 15) * 4] = v;
    }
    {
        int r = t >> 2, n0 = (t & 3) * 4;
        ushort4 cu4 = *(const ushort4*)&Cpost[((size_t)b * LL + l0 + r) * DSTATE + n0];
        Cs[r][n0 + 0] = bf2f(cu4.x);
        Cs[r][n0 + 1] = bf2f(cu4.y);
        Cs[r][n0 + 2] = bf2f(cu4.z);
        Cs[r][n0 + 3] = bf2f(cu4.w);
        int hh2 = t & 3;
        cds[r][hh2] = cdecbuf[((size_t)(b * 4 + hh2)) * LL + l0 + r];
    }

    // inline chunk-level scan: H = sum_{c'<=ck} Sraw[c'] * prod decays (same order as old k3b)
    float4 H[4][4];
    #pragma unroll
    for (int k = 0; k < 4; ++k)
        #pragma unroll
        for (int n4 = 0; n4 < 4; ++n4)
            H[k][n4] = make_float4(0.f, 0.f, 0.f, 0.f);
    for (int cc = 1; cc <= ck; ++cc) {
        float P = cdecbuf[((size_t)(b * 4 + hh)) * LL + cc * CS - 1];
        const float* sb = h0buf + (((size_t)(b * 4 + hh)) * NCH + cc) * 1024 + p0 * 16;
        #pragma unroll
        for (int k = 0; k < 4; ++k) {
            #pragma unroll
            for (int n4 = 0; n4 < 4; ++n4) {
                float4 S = *(const float4*)&sb[k * 16 + n4 * 4];
                H[k][n4].x = fmaf(H[k][n4].x, P, S.x);
                H[k][n4].y = fmaf(H[k][n4].y, P, S.y);
                H[k][n4].z = fmaf(H[k][n4].z, P, S.z);
                H[k][n4].w = fmaf(H[k][n4].w, P, S.w);
            }
        }
    }
    __syncthreads();

    // rstd per row
    {
        int row = t >> 2, part = t & 3;
        float ss = 0.f;
        #pragma unroll
        for (int jj = 0; jj < 16; ++jj) { float v = s.u[row][part * 16 + jj]; ss = fmaf(v, v, ss); }
        ss += __shfl_xor(ss, 1); ss += __shfl_xor(ss, 2);
        if (part == 0) rstd[row] = rsqrtf(ss * (1.f / 64.f) + EPSF);
    }
    __syncthreads();

    // bf16 A-fragments (RMSNorm + block_norm folded)
    float4 bw[2][2];
    bw[0][0] = *(const float4*)&bnw[kb];
    bw[0][1] = *(const float4*)&bnw[kb + 4];
    bw[1][0] = *(const float4*)&bnw[32 + kb];
    bw[1][1] = *(const float4*)&bnw[32 + kb + 4];
    bf16x8 af[4][2];
    #pragma unroll
    for (int mt = 0; mt < 4; ++mt) {
        float rs = rstd[mt * 16 + a];
        #pragma unroll
        for (int kk = 0; kk < 2; ++kk) {
            float4 v0 = *(const float4*)&s.u[mt * 16 + a][kk * 32 + kb];
            float4 v1 = *(const float4*)&s.u[mt * 16 + a][kk * 32 + kb + 4];
            ushort* p = (ushort*)&af[mt][kk];
            p[0] = f2bf(v0.x * rs * bw[kk][0].x);
            p[1] = f2bf(v0.y * rs * bw[kk][0].y);
            p[2] = f2bf(v0.z * rs * bw[kk][0].z);
            p[3] = f2bf(v0.w * rs * bw[kk][0].w);
            p[4] = f2bf(v1.x * rs * bw[kk][1].x);
            p[5] = f2bf(v1.y * rs * bw[kk][1].y);
            p[6] = f2bf(v1.z * rs * bw[kk][1].z);
            p[7] = f2bf(v1.w * rs * bw[kk][1].w);
        }
    }
    // residual x values (before u is overwritten)
    float xres[16];
    #pragma unroll
    for (int mt = 0; mt < 4; ++mt)
        #pragma unroll
        for (int r = 0; r < 4; ++r)
            xres[mt * 4 + r] = s.u[mt * 16 + (l >> 4) * 4 + r][16 * w + j];
    __syncthreads();   // u dead -> zg writes allowed

    // z-GEMM (fp32 weights inline-cvt); store silu(z)
    #pragma unroll
    for (int ct4 = 0; ct4 < 4; ++ct4) {
        int ct = w * 4 + ct4;
        const float* wrow = Wfp + (size_t)(ct * 16 + a) * 64 + kb;
        bf16x8 b0 = pack8(*(const float4*)&wrow[0],  *(const float4*)&wrow[4]);
        bf16x8 b1 = pack8(*(const float4*)&wrow[32], *(const float4*)&wrow[36]);
        #pragma unroll
        for (int mt = 0; mt < 4; ++mt) {
            f32x4 acc = {0.f, 0.f, 0.f, 0.f};
            acc = __builtin_amdgcn_mfma_f32_16x16x32_bf16(af[mt][0], b0, acc, 0, 0, 0);
            acc = __builtin_amdgcn_mfma_f32_16x16x32_bf16(af[mt][1], b1, acc, 0, 0, 0);
            int row0 = mt * 16 + (l >> 4) * 4;
            int col = ct * 16 + a;
            #pragma unroll
            for (int r = 0; r < 4; ++r) s.zg[row0 + r][col] = f2bf(fsilu(acc[r]));
        }
    }
    __syncthreads();

    const float4 ng4 = *(const float4*)&ngw[ch4];

    // gate + correction + RMSNorm; in-place zg -> g
    #pragma unroll
    for (int i = 0; i < 16; ++i) {
        int row = i * 4 + w;
        ushort4 yu = *(const ushort4*)&yb[(size_t)row * DINN + ch4];
        ushort4 zu = *(const ushort4*)&s.zg[row][ch4];
        float4 yv = { bf2f(yu.x), bf2f(yu.y), bf2f(yu.z), bf2f(yu.w) };
        float4 zv = { bf2f(zu.x), bf2f(zu.y), bf2f(zu.z), bf2f(zu.w) };  // silu(z)
        float4 C0 = *(const float4*)&Cs[row][0];
        float4 C1 = *(const float4*)&Cs[row][4];
        float4 C2 = *(const float4*)&Cs[row][8];
        float4 C3 = *(const float4*)&Cs[row][12];
        float cdv = cds[row][hh];
        float corr[4];
        #pragma unroll
        for (int k = 0; k < 4; ++k) {
            float sc = H[k][0].x * C0.x + H[k][0].y * C0.y + H[k][0].z * C0.z + H[k][0].w * C0.w;
            sc += H[k][1].x * C1.x + H[k][1].y * C1.y + H[k][1].z * C1.z + H[k][1].w * C1.w;
            sc += H[k][2].x * C2.x + H[k][2].y * C2.y + H[k][2].z * C2.z + H[k][2].w * C2.w;
            sc += H[k][3].x * C3.x + H[k][3].y * C3.y + H[k][3].z * C3.z + H[k][3].w * C3.w;
            corr[k] = sc * cdv;
        }
        float4 gv;
        gv.x = (yv.x + corr[0]) * zv.x;
        gv.y = (yv.y + corr[1]) * zv.y;
        gv.z = (yv.z + corr[2]) * zv.z;
        gv.w = (yv.w + corr[3]) * zv.w;
        float sq = gv.x * gv.x + gv.y * gv.y + gv.z * gv.z + gv.w * gv.w;
        sq += __shfl_xor(sq, 1);  sq += __shfl_xor(sq, 2);  sq += __shfl_xor(sq, 4);
        sq += __shfl_xor(sq, 8);  sq += __shfl_xor(sq, 16); sq += __shfl_xor(sq, 32);
        float rs = rsqrtf(sq * (1.f / 256.f) + EPSF);
        ushort4 o;
        o.x = f2bf(gv.x * rs * ng4.x);
        o.y = f2bf(gv.y * rs * ng4.y);
        o.z = f2bf(gv.z * rs * ng4.z);
        o.w = f2bf(gv.w * rs * ng4.w);
        *(ushort4*)&s.zg[row][ch4] = o;
    }
    __syncthreads();

    // out_proj (fp32 weights inline-cvt)
    bf16x8 bf[8];
    #pragma unroll
    for (int ks = 0; ks < 8; ++ks) {
        const float* wo = Wofp + (size_t)(16 * w + j) * DINN + ks * 32 + kb;
        bf[ks] = pack8(*(const float4*)&wo[0], *(const float4*)&wo[4]);
    }
    #pragma unroll
    for (int mt = 0; mt < 4; ++mt) {
        f32x4 acc = {0.f, 0.f, 0.f, 0.f};
        #pragma unroll
        for (int ks = 0; ks < 8; ++ks) {
            bf16x8 ag = *(const bf16x8*)&s.zg[mt * 16 + j][ks * 32 + kb];
            acc = __builtin_amdgcn_mfma_f32_16x16x32_bf16(ag, bf[ks], acc, 0, 0, 0);
        }
        #pragma unroll
        for (int r = 0; r < 4; ++r) {
            size_t row = (size_t)m0 + mt * 16 + (l >> 4) * 4 + r;
            size_t oidx = row * 64 + 16 * w + j;
            out[oidx] = acc[r] + 2.f * xres[mt * 4 + r];
        }
    }
}

extern "C" void kernel_launch(void* const* d_in, const int* in_sizes, int n_in,
                              void* d_out, int out_size, void* d_ws, size_t ws_size,
                              hipStream_t stream) {
    const float* x          = (const float*)d_in[0];
    const float* in_proj_w  = (const float*)d_in[1];
    const float* conv_w     = (const float*)d_in[2];
    const float* conv_b     = (const float*)d_in[3];
    const float* dt_bias    = (const float*)d_in[4];
    const float* A_log      = (const float*)d_in[5];
    const float* D          = (const float*)d_in[6];
    const float* norm_gate  = (const float*)d_in[7];
    const float* out_proj_w = (const float*)d_in[8];
    const float* block_norm = (const float*)d_in[9];
    float* out = (float*)d_out;

    float* h0b   = (float*)d_ws;                               //  2,097,152 f32
    float* cdec  = h0b  + (size_t)BB * NHEADS * NCH * 1024;    //    131,072 f32
    float* dtb   = cdec + (size_t)BB * NHEADS * LL;            //    131,072 f32
    ushort* Cp   = (ushort*)(dtb + (size_t)BB * NHEADS * LL);  //    524,288 us
    ushort* ybf  = Cp   + (size_t)BB * LL * DSTATE;            //  8,388,608 us
    ushort* xbc  = ybf  + (size_t)BB * LL * DINN;              //  9,437,184 us

    k1_mfma<<<512, 256, 0, stream>>>(x, in_proj_w, block_norm, dt_bias, xbc, dtb);
    k3a_ssd<<<2048, 256, 0, stream>>>(xbc, dtb, conv_w, conv_b, A_log, D, ybf, h0b, cdec, Cp);
    k4_out<<<512, 256, 0, stream>>>(ybf, norm_gate, out_proj_w, in_proj_w, block_norm, x, h0b, cdec, Cp, out);
}

// Round 15
// 68.031 us; speedup vs baseline: 1.7382x; 1.7382x over previous
//
#include <hip/hip_runtime.h>
#include <math.h>

#define BB 32
#define LL 1024
#define DIMM 64
#define DINN 256
#define NHEADS 4
#define DSTATE 16
#define DINPROJ 548
#define EPSF 1e-5f
#define NCH 16    // chunks per sequence
#define CS 64     // chunk size

typedef __attribute__((ext_vector_type(8))) short bf16x8;
typedef __attribute__((ext_vector_type(4))) float f32x4;

__device__ inline ushort f2bf(float f) {
    union { float f; unsigned u; } v; v.f = f;
    unsigned r = (v.u + 0x7FFFu + ((v.u >> 16) & 1u)) >> 16;
    return (ushort)r;
}
__device__ inline float bf2f(ushort u) {
    union { float f; unsigned u; } v; v.u = ((unsigned)u) << 16; return v.f;
}
__device__ inline float fexp(float v) { return __expf(v); }
__device__ inline float fsilu(float v) {
    return v * __builtin_amdgcn_rcpf(1.f + __expf(-v));
}
__device__ inline bf16x8 pack8(float4 a, float4 b) {
    bf16x8 r; ushort* p = (ushort*)&r;
    p[0] = f2bf(a.x); p[1] = f2bf(a.y); p[2] = f2bf(a.z); p[3] = f2bf(a.w);
    p[4] = f2bf(b.x); p[5] = f2bf(b.y); p[6] = f2bf(b.z); p[7] = f2bf(b.w);
    return r;
}

// -- K1: M=64; RMSNorm + in_proj xBC (bf16 MFMA, fp32 weights inline-cvt) + dt --
// grid 512, block 256 = 4 waves
__global__ __launch_bounds__(256) void k1_mfma(
        const float* __restrict__ x, const float* __restrict__ Wfp,
        const float* __restrict__ bnw, const float* __restrict__ dt_bias,
        ushort* __restrict__ xbcbuf, float* __restrict__ dtbuf) {
    __shared__ __align__(16) union {
        struct { float u[64][68]; float wdt[4][68]; } a;   // 18.5 KB
        ushort ob[64][296];                                 // 37.9 KB
    } s;
    __shared__ float rstd[64];
    const int t = threadIdx.x;
    const int m0 = blockIdx.x * 64;
    const int b = m0 >> 10;
    const int lbase = m0 & 1023;

    const float* xrow = x + (size_t)m0 * 64;
    #pragma unroll
    for (int i = 0; i < 4; ++i) {
        int idx = t + i * 256;
        float4 v = ((const float4*)xrow)[idx];
        *(float4*)&s.a.u[idx >> 4][(idx & 15) * 4] = v;
    }
    s.a.wdt[t >> 6][t & 63] = Wfp[(size_t)(544 + (t >> 6)) * 64 + (t & 63)] * bnw[t & 63];
    __syncthreads();
    {
        int row = t >> 2, part = t & 3;
        float ss = 0.f;
        #pragma unroll
        for (int j = 0; j < 16; ++j) { float v = s.a.u[row][part * 16 + j]; ss = fmaf(v, v, ss); }
        ss += __shfl_xor(ss, 1); ss += __shfl_xor(ss, 2);
        if (part == 0) rstd[row] = rsqrtf(ss * (1.f / 64.f) + EPSF);
    }
    __syncthreads();

    const int w = t >> 6, l = t & 63;
    const int a = l & 15, kb = (l >> 4) * 8;

    float4 bw[2][2];
    bw[0][0] = *(const float4*)&bnw[kb];
    bw[0][1] = *(const float4*)&bnw[kb + 4];
    bw[1][0] = *(const float4*)&bnw[32 + kb];
    bw[1][1] = *(const float4*)&bnw[32 + kb + 4];

    bf16x8 af[4][2];
    #pragma unroll
    for (int mt = 0; mt < 4; ++mt) {
        float rs = rstd[mt * 16 + a];
        #pragma unroll
        for (int kk = 0; kk < 2; ++kk) {
            float4 v0 = *(const float4*)&s.a.u[mt * 16 + a][kk * 32 + kb];
            float4 v1 = *(const float4*)&s.a.u[mt * 16 + a][kk * 32 + kb + 4];
            ushort* p = (ushort*)&af[mt][kk];
            p[0] = f2bf(v0.x * rs * bw[kk][0].x);
            p[1] = f2bf(v0.y * rs * bw[kk][0].y);
            p[2] = f2bf(v0.z * rs * bw[kk][0].z);
            p[3] = f2bf(v0.w * rs * bw[kk][0].w);
            p[4] = f2bf(v1.x * rs * bw[kk][1].x);
            p[5] = f2bf(v1.y * rs * bw[kk][1].y);
            p[6] = f2bf(v1.z * rs * bw[kk][1].z);
            p[7] = f2bf(v1.w * rs * bw[kk][1].w);
        }
    }

    // fp32 dt + softplus (all 256 threads: 64 rows x 4 heads)
    {
        int row = t >> 2, h = t & 3;
        const float* ur = s.a.u[row];
        const float* wr = s.a.wdt[h];
        float sd = 0.f;
        #pragma unroll
        for (int k4 = 0; k4 < 16; ++k4) {
            float4 uv = *(const float4*)&ur[k4 * 4];
            float4 wv = *(const float4*)&wr[k4 * 4];
            sd = fmaf(uv.x, wv.x, sd); sd = fmaf(uv.y, wv.y, sd);
            sd = fmaf(uv.z, wv.z, sd); sd = fmaf(uv.w, wv.w, sd);
        }
        sd = sd * rstd[row] + dt_bias[h];
        sd = fmaxf(sd, 0.f) + log1pf(expf(-fabsf(sd)));   // keep precise
        dtbuf[((size_t)(b * 4 + h)) * LL + lbase + row] = sd;
    }
    __syncthreads();   // u/wdt dead; ob may now be written

    // xBC columns: nt = 16..33, fp32 weights converted inline
    for (int nt = 16 + w; nt < 34; nt += 4) {
        const float* wrow = Wfp + (size_t)(nt * 16 + a) * 64 + kb;
        bf16x8 b0 = pack8(*(const float4*)&wrow[0],  *(const float4*)&wrow[4]);
        bf16x8 b1 = pack8(*(const float4*)&wrow[32], *(const float4*)&wrow[36]);
        #pragma unroll
        for (int mt = 0; mt < 4; ++mt) {
            f32x4 acc = {0.f, 0.f, 0.f, 0.f};
            acc = __builtin_amdgcn_mfma_f32_16x16x32_bf16(af[mt][0], b0, acc, 0, 0, 0);
            acc = __builtin_amdgcn_mfma_f32_16x16x32_bf16(af[mt][1], b1, acc, 0, 0, 0);
            int row0 = mt * 16 + (l >> 4) * 4;
            int col = nt * 16 + a - 256;
            #pragma unroll
            for (int r = 0; r < 4; ++r) s.ob[row0 + r][col] = f2bf(acc[r]);
        }
    }
    __syncthreads();

    for (int i = t; i < 2304; i += 256) {           // 64 rows x 36 chunks
        int row = i / 36, c8 = (i % 36) * 8;
        *(uint4*)&xbcbuf[(size_t)(m0 + row) * 288 + c8] = *(const uint4*)&s.ob[row][c8];
    }
}

// ---------------- K3a: SSD chunked scan via MFMA (bf16 in/out) ----------------
__global__ __launch_bounds__(256) void k3a_ssd(
        const ushort* __restrict__ xbcbuf, const float* __restrict__ dtbuf,
        const float* __restrict__ conv_w, const float* __restrict__ conv_b,
        const float* __restrict__ A_log, const float* __restrict__ Dp,
        ushort* __restrict__ y, float* __restrict__ h0buf,
        float* __restrict__ cdecbuf, ushort* __restrict__ Cpost) {
    const int bid = blockIdx.x;
    const int c = bid & 15, h = (bid >> 4) & 3, b = bid >> 6;
    const int t = threadIdx.x;

    __shared__ __align__(16) union {
        struct { ushort rawx[67][64]; ushort rawbc[67][32]; } st;
        struct { ushort Mb[64][72]; ushort BwT[16][72]; } ssd;
    } uu;
    __shared__ ushort XbT[64][72];
    __shared__ ushort Bb[64][40];
    __shared__ ushort Cb[64][40];
    __shared__ float dtt[64], laa[64], ww[64];

    const float A  = -expf(A_log[h]);
    const float Dh = Dp[h];
    const int l0 = c * CS;
    const ushort* xb = xbcbuf + (size_t)b * LL * 288;

    for (int i = t; i < 67 * 32; i += 256) {
        int r = i >> 5, cu = i & 31;
        int l = l0 - 3 + r;
        ((uint*)&uu.st.rawx[r][0])[cu] =
            (l >= 0) ? ((const uint*)(xb + (size_t)l * 288 + h * 64))[cu] : 0u;
    }
    for (int i = t; i < 67 * 16; i += 256) {
        int r = i >> 4, cu = i & 15;
        int l = l0 - 3 + r;
        ((uint*)&uu.st.rawbc[r][0])[cu] =
            (l >= 0) ? ((const uint*)(xb + (size_t)l * 288 + 256))[cu] : 0u;
    }
    for (int i = t; i < 512; i += 256) {
        int r = i >> 3, cc = i & 7;
        ((uint*)&Bb[r][16])[cc] = 0;
        ((uint*)&Cb[r][16])[cc] = 0;
    }
    if (t < 64) {
        float dv = dtbuf[((size_t)(b * 4 + h)) * LL + l0 + t];
        float run = dv * A;
        #pragma unroll
        for (int off = 1; off < 64; off <<= 1) {
            float o = __shfl_up(run, off, 64);
            if (t >= off) run += o;
        }
        dtt[t] = dv;
        laa[t] = run;
        cdecbuf[((size_t)(b * 4 + h)) * LL + l0 + t] = fexp(run);
        float laEnd = __shfl(run, 63, 64);
        ww[t] = dv * fexp(laEnd - run);
    }
    __syncthreads();

    {
        const int jx = t & 63;
        const int w0 = (t >> 6) * 16;
        const int cx = h * 64 + jx;
        const float4 cwx = *(const float4*)&conv_w[cx * 4];
        const float  cbx = conv_b[cx];
        float r0[19];
        #pragma unroll
        for (int k = 0; k < 19; ++k) r0[k] = bf2f(uu.st.rawx[w0 + k][jx]);
        ushort vv[16];
        #pragma unroll
        for (int k = 0; k < 16; ++k) {
            float v = cbx + r0[k] * cwx.x + r0[k + 1] * cwx.y
                          + r0[k + 2] * cwx.z + r0[k + 3] * cwx.w;
            vv[k] = f2bf(fsilu(v));
        }
        *(bf16x8*)&XbT[jx][w0]     = *(bf16x8*)&vv[0];
        *(bf16x8*)&XbT[jx][w0 + 8] = *(bf16x8*)&vv[8];

        const int jbc = t & 31, cbc = 256 + jbc;
        const float4 cwb = *(const float4*)&conv_w[cbc * 4];
        const float  cbb = conv_b[cbc];
        #pragma unroll
        for (int i = 0; i < 8; ++i) {
            int ss = (t >> 5) + i * 8;
            float v = cbb + bf2f(uu.st.rawbc[ss][jbc]) * cwb.x
                          + bf2f(uu.st.rawbc[ss + 1][jbc]) * cwb.y
                          + bf2f(uu.st.rawbc[ss + 2][jbc]) * cwb.z
                          + bf2f(uu.st.rawbc[ss + 3][jbc]) * cwb.w;
            v = fsilu(v);
            if (jbc < 16) Bb[ss][jbc] = f2bf(v);
            else {
                ushort bv = f2bf(v);
                Cb[ss][jbc - 16] = bv;
                Cpost[((size_t)b * LL + l0 + ss) * DSTATE + (jbc - 16)] = bv;
            }
        }
    }
    __syncthreads();

    const int w = t >> 6, l = t & 63;
    const int fr = l & 15, fq = l >> 4;

    f32x4 gacc[4];
    {
        bf16x8 ca = *(const bf16x8*)&Cb[w * 16 + fr][fq * 8];
        #pragma unroll
        for (int jt = 0; jt < 4; ++jt) {
            bf16x8 bb = *(const bf16x8*)&Bb[jt * 16 + fr][fq * 8];
            f32x4 z = {0.f, 0.f, 0.f, 0.f};
            gacc[jt] = __builtin_amdgcn_mfma_f32_16x16x32_bf16(ca, bb, z, 0, 0, 0);
        }
    }
    #pragma unroll
    for (int jt = 0; jt < 4; ++jt) {
        int j = jt * 16 + fr;
        float laj = laa[j], dtj = dtt[j];
        #pragma unroll
        for (int r = 0; r < 4; ++r) {
            int i = w * 16 + fq * 4 + r;
            float m = (j <= i) ? gacc[jt][r] * fexp(laa[i] - laj) * dtj : 0.f;
            uu.ssd.Mb[i][j] = f2bf(m);
        }
    }
    #pragma unroll
    for (int i2 = 0; i2 < 4; ++i2) {
        int idx = t + i2 * 256;
        int n = idx & 15, jj = idx >> 4;
        uu.ssd.BwT[n][jj] = f2bf(ww[jj] * bf2f(Bb[jj][n]));
    }

    {
        bf16x8 ma0 = *(const bf16x8*)&uu.ssd.Mb[w * 16 + fr][fq * 8];
        bf16x8 ma1 = *(const bf16x8*)&uu.ssd.Mb[w * 16 + fr][32 + fq * 8];
        #pragma unroll
        for (int pt = 0; pt < 4; ++pt) {
            bf16x8 xb0 = *(const bf16x8*)&XbT[pt * 16 + fr][fq * 8];
            bf16x8 xb1 = *(const bf16x8*)&XbT[pt * 16 + fr][32 + fq * 8];
            f32x4 acc = {0.f, 0.f, 0.f, 0.f};
            acc = __builtin_amdgcn_mfma_f32_16x16x32_bf16(ma0, xb0, acc, 0, 0, 0);
            acc = __builtin_amdgcn_mfma_f32_16x16x32_bf16(ma1, xb1, acc, 0, 0, 0);
            #pragma unroll
            for (int r = 0; r < 4; ++r) {
                int i = w * 16 + fq * 4 + r;
                int p = pt * 16 + fr;
                float xv = bf2f(XbT[p][i]);
                uu.ssd.Mb[i][p] = f2bf(acc[r] + Dh * xv);
            }
        }
    }
    __syncthreads();

    if (c < 15) {
        bf16x8 xa0 = *(const bf16x8*)&XbT[w * 16 + fr][fq * 8];
        bf16x8 xa1 = *(const bf16x8*)&XbT[w * 16 + fr][32 + fq * 8];
        bf16x8 bw0 = *(const bf16x8*)&uu.ssd.BwT[fr][fq * 8];
        bf16x8 bw1 = *(const bf16x8*)&uu.ssd.BwT[fr][32 + fq * 8];
        f32x4 acc = {0.f, 0.f, 0.f, 0.f};
        acc = __builtin_amdgcn_mfma_f32_16x16x32_bf16(xa0, bw0, acc, 0, 0, 0);
        acc = __builtin_amdgcn_mfma_f32_16x16x32_bf16(xa1, bw1, acc, 0, 0, 0);
        float* Sdst = h0buf + (((size_t)(b * 4 + h)) * NCH + (c + 1)) * 1024;
        #pragma unroll
        for (int r = 0; r < 4; ++r) {
            int p = w * 16 + fq * 4 + r;
            Sdst[p * 16 + fr] = acc[r];
        }
    }

    {
        ushort* ybase = y + ((size_t)b * LL + l0) * DINN + h * 64;
        #pragma unroll
        for (int ii = 0; ii < 2; ++ii) {
            int idx = t + ii * 256;
            int row = idx >> 3, c8 = (idx & 7) * 8;
            *(uint4*)&ybase[(size_t)row * DINN + c8] = *(const uint4*)&uu.ssd.Mb[row][c8];
        }
    }
}

// ---------------- K3b: chunk-level scan (16 chunks) ----------------
__global__ __launch_bounds__(256) void k3b_chunkscan(
        float* __restrict__ h0buf, const float* __restrict__ cdecbuf) {
    const int bh = blockIdx.x;
    const int t = threadIdx.x;
    float* base = h0buf + (size_t)bh * NCH * 1024;
    const float* cd = cdecbuf + (size_t)bh * LL;
    float4 run = {0.f, 0.f, 0.f, 0.f};
    *(float4*)&base[(size_t)t * 4] = run;
    #pragma unroll
    for (int c = 1; c < NCH; ++c) {
        float P = cd[c * CS - 1];
        float4 S = *(float4*)&base[(size_t)c * 1024 + t * 4];
        run.x = fmaf(run.x, P, S.x);
        run.y = fmaf(run.y, P, S.y);
        run.z = fmaf(run.z, P, S.z);
        run.w = fmaf(run.w, P, S.w);
        *(float4*)&base[(size_t)c * 1024 + t * 4] = run;
    }
}

// ---- K4: z recompute (inline-cvt) + correction (H regs) + gate + RMSNorm + out_proj ----
// grid 512 = (b, chunk); block 256 = 4 waves
__global__ __launch_bounds__(256) void k4_out(
        const ushort* __restrict__ ybf, const float* __restrict__ ngw,
        const float* __restrict__ Wofp, const float* __restrict__ Wfp,
        const float* __restrict__ bnw, const float* __restrict__ x,
        const float* __restrict__ h0buf, const float* __restrict__ cdecbuf,
        const ushort* __restrict__ Cpost, float* __restrict__ out) {
    __shared__ __align__(16) union {
        float u[64][68];        // 17.4 KB (phase A)
        ushort zg[64][264];     // 33.8 KB (silu(z) then g)
    } s;
    __shared__ float Cs[64][16];
    __shared__ float cds[64][4];
    __shared__ float rstd[64];
    const int t = threadIdx.x;
    const int m0 = blockIdx.x * 64;
    const int b  = m0 >> 10;
    const int l0 = m0 & 1023;
    const int ck = l0 >> 6;
    const ushort* yb = ybf + (size_t)m0 * DINN;

    const int w = t >> 6, l = t & 63;
    const int ch4 = l * 4;
    const int hh  = ch4 >> 6;
    const int p0  = ch4 & 63;
    const int a = l & 15, kb = (l >> 4) * 8;
    const int j = l & 15;

    // H register loads from the scanned h0buf (independent, issued first)
    const float* hbase = h0buf + (((size_t)(b * 4 + hh)) * NCH + ck) * 1024 + p0 * 16;
    float4 H[4][4];
    #pragma unroll
    for (int k = 0; k < 4; ++k)
        #pragma unroll
        for (int n4 = 0; n4 < 4; ++n4)
            H[k][n4] = *(const float4*)&hbase[k * 16 + n4 * 4];

    // stage x tile (64 x 64 fp32), C, cdec
    const float* xrow = x + (size_t)m0 * 64;
    #pragma unroll
    for (int i = 0; i < 4; ++i) {
        int idx = t + i * 256;
        float4 v = ((const float4*)xrow)[idx];
        *(float4*)&s.u[idx >> 4][(idx & 15) * 4] = v;
    }
    {
        int r = t >> 2, n0 = (t & 3) * 4;
        ushort4 cu4 = *(const ushort4*)&Cpost[((size_t)b * LL + l0 + r) * DSTATE + n0];
        Cs[r][n0 + 0] = bf2f(cu4.x);
        Cs[r][n0 + 1] = bf2f(cu4.y);
        Cs[r][n0 + 2] = bf2f(cu4.z);
        Cs[r][n0 + 3] = bf2f(cu4.w);
        int hh2 = t & 3;
        cds[r][hh2] = cdecbuf[((size_t)(b * 4 + hh2)) * LL + l0 + r];
    }
    __syncthreads();

    // rstd per row
    {
        int row = t >> 2, part = t & 3;
        float ss = 0.f;
        #pragma unroll
        for (int jj = 0; jj < 16; ++jj) { float v = s.u[row][part * 16 + jj]; ss = fmaf(v, v, ss); }
        ss += __shfl_xor(ss, 1); ss += __shfl_xor(ss, 2);
        if (part == 0) rstd[row] = rsqrtf(ss * (1.f / 64.f) + EPSF);
    }
    __syncthreads();

    // bf16 A-fragments (RMSNorm + block_norm folded)
    float4 bw[2][2];
    bw[0][0] = *(const float4*)&bnw[kb];
    bw[0][1] = *(const float4*)&bnw[kb + 4];
    bw[1][0] = *(const float4*)&bnw[32 + kb];
    bw[1][1] = *(const float4*)&bnw[32 + kb + 4];
    bf16x8 af[4][2];
    #pragma unroll
    for (int mt = 0; mt < 4; ++mt) {
        float rs = rstd[mt * 16 + a];
        #pragma unroll
        for (int kk = 0; kk < 2; ++kk) {
            float4 v0 = *(const float4*)&s.u[mt * 16 + a][kk * 32 + kb];
            float4 v1 = *(const float4*)&s.u[mt * 16 + a][kk * 32 + kb + 4];
            ushort* p = (ushort*)&af[mt][kk];
            p[0] = f2bf(v0.x * rs * bw[kk][0].x);
            p[1] = f2bf(v0.y * rs * bw[kk][0].y);
            p[2] = f2bf(v0.z * rs * bw[kk][0].z);
            p[3] = f2bf(v0.w * rs * bw[kk][0].w);
            p[4] = f2bf(v1.x * rs * bw[kk][1].x);
            p[5] = f2bf(v1.y * rs * bw[kk][1].y);
            p[6] = f2bf(v1.z * rs * bw[kk][1].z);
            p[7] = f2bf(v1.w * rs * bw[kk][1].w);
        }
    }
    // residual x values (before u is overwritten)
    float xres[16];
    #pragma unroll
    for (int mt = 0; mt < 4; ++mt)
        #pragma unroll
        for (int r = 0; r < 4; ++r)
            xres[mt * 4 + r] = s.u[mt * 16 + (l >> 4) * 4 + r][16 * w + j];
    __syncthreads();   // u dead -> zg writes allowed

    // z-GEMM (fp32 weights inline-cvt); store silu(z)
    #pragma unroll
    for (int ct4 = 0; ct4 < 4; ++ct4) {
        int ct = w * 4 + ct4;
        const float* wrow = Wfp + (size_t)(ct * 16 + a) * 64 + kb;
        bf16x8 b0 = pack8(*(const float4*)&wrow[0],  *(const float4*)&wrow[4]);
        bf16x8 b1 = pack8(*(const float4*)&wrow[32], *(const float4*)&wrow[36]);
        #pragma unroll
        for (int mt = 0; mt < 4; ++mt) {
            f32x4 acc = {0.f, 0.f, 0.f, 0.f};
            acc = __builtin_amdgcn_mfma_f32_16x16x32_bf16(af[mt][0], b0, acc, 0, 0, 0);
            acc = __builtin_amdgcn_mfma_f32_16x16x32_bf16(af[mt][1], b1, acc, 0, 0, 0);
            int row0 = mt * 16 + (l >> 4) * 4;
            int col = ct * 16 + a;
            #pragma unroll
            for (int r = 0; r < 4; ++r) s.zg[row0 + r][col] = f2bf(fsilu(acc[r]));
        }
    }
    __syncthreads();

    const float4 ng4 = *(const float4*)&ngw[ch4];

    // gate + correction + RMSNorm; in-place zg -> g
    #pragma unroll
    for (int i = 0; i < 16; ++i) {
        int row = i * 4 + w;
        ushort4 yu = *(const ushort4*)&yb[(size_t)row * DINN + ch4];
        ushort4 zu = *(const ushort4*)&s.zg[row][ch4];
        float4 yv = { bf2f(yu.x), bf2f(yu.y), bf2f(yu.z), bf2f(yu.w) };
        float4 zv = { bf2f(zu.x), bf2f(zu.y), bf2f(zu.z), bf2f(zu.w) };  // silu(z)
        float4 C0 = *(const float4*)&Cs[row][0];
        float4 C1 = *(const float4*)&Cs[row][4];
        float4 C2 = *(const float4*)&Cs[row][8];
        float4 C3 = *(const float4*)&Cs[row][12];
        float cdv = cds[row][hh];
        float corr[4];
        #pragma unroll
        for (int k = 0; k < 4; ++k) {
            float sc = H[k][0].x * C0.x + H[k][0].y * C0.y + H[k][0].z * C0.z + H[k][0].w * C0.w;
            sc += H[k][1].x * C1.x + H[k][1].y * C1.y + H[k][1].z * C1.z + H[k][1].w * C1.w;
            sc += H[k][2].x * C2.x + H[k][2].y * C2.y + H[k][2].z * C2.z + H[k][2].w * C2.w;
            sc += H[k][3].x * C3.x + H[k][3].y * C3.y + H[k][3].z * C3.z + H[k][3].w * C3.w;
            corr[k] = sc * cdv;
        }
        float4 gv;
        gv.x = (yv.x + corr[0]) * zv.x;
        gv.y = (yv.y + corr[1]) * zv.y;
        gv.z = (yv.z + corr[2]) * zv.z;
        gv.w = (yv.w + corr[3]) * zv.w;
        float sq = gv.x * gv.x + gv.y * gv.y + gv.z * gv.z + gv.w * gv.w;
        sq += __shfl_xor(sq, 1);  sq += __shfl_xor(sq, 2);  sq += __shfl_xor(sq, 4);
        sq += __shfl_xor(sq, 8);  sq += __shfl_xor(sq, 16); sq += __shfl_xor(sq, 32);
        float rs = rsqrtf(sq * (1.f / 256.f) + EPSF);
        ushort4 o;
        o.x = f2bf(gv.x * rs * ng4.x);
        o.y = f2bf(gv.y * rs * ng4.y);
        o.z = f2bf(gv.z * rs * ng4.z);
        o.w = f2bf(gv.w * rs * ng4.w);
        *(ushort4*)&s.zg[row][ch4] = o;
    }
    __syncthreads();

    // out_proj (fp32 weights inline-cvt)
    bf16x8 bf[8];
    #pragma unroll
    for (int ks = 0; ks < 8; ++ks) {
        const float* wo = Wofp + (size_t)(16 * w + j) * DINN + ks * 32 + kb;
        bf[ks] = pack8(*(const float4*)&wo[0], *(const float4*)&wo[4]);
    }
    #pragma unroll
    for (int mt = 0; mt < 4; ++mt) {
        f32x4 acc = {0.f, 0.f, 0.f, 0.f};
        #pragma unroll
        for (int ks = 0; ks < 8; ++ks) {
            bf16x8 ag = *(const bf16x8*)&s.zg[mt * 16 + j][ks * 32 + kb];
            acc = __builtin_amdgcn_mfma_f32_16x16x32_bf16(ag, bf[ks], acc, 0, 0, 0);
        }
        #pragma unroll
        for (int r = 0; r < 4; ++r) {
            size_t row = (size_t)m0 + mt * 16 + (l >> 4) * 4 + r;
            size_t oidx = row * 64 + 16 * w + j;
            out[oidx] = acc[r] + 2.f * xres[mt * 4 + r];
        }
    }
}

extern "C" void kernel_launch(void* const* d_in, const int* in_sizes, int n_in,
                              void* d_out, int out_size, void* d_ws, size_t ws_size,
                              hipStream_t stream) {
    const float* x          = (const float*)d_in[0];
    const float* in_proj_w  = (const float*)d_in[1];
    const float* conv_w     = (const float*)d_in[2];
    const float* conv_b     = (const float*)d_in[3];
    const float* dt_bias    = (const float*)d_in[4];
    const float* A_log      = (const float*)d_in[5];
    const float* D          = (const float*)d_in[6];
    const float* norm_gate  = (const float*)d_in[7];
    const float* out_proj_w = (const float*)d_in[8];
    const float* block_norm = (const float*)d_in[9];
    float* out = (float*)d_out;

    float* h0b   = (float*)d_ws;                               //  2,097,152 f32
    float* cdec  = h0b  + (size_t)BB * NHEADS * NCH * 1024;    //    131,072 f32
    float* dtb   = cdec + (size_t)BB * NHEADS * LL;            //    131,072 f32
    ushort* Cp   = (ushort*)(dtb + (size_t)BB * NHEADS * LL);  //    524,288 us
    ushort* ybf  = Cp   + (size_t)BB * LL * DSTATE;            //  8,388,608 us
    ushort* xbc  = ybf  + (size_t)BB * LL * DINN;              //  9,437,184 us

    k1_mfma<<<512, 256, 0, stream>>>(x, in_proj_w, block_norm, dt_bias, xbc, dtb);
    k3a_ssd<<<2048, 256, 0, stream>>>(xbc, dtb, conv_w, conv_b, A_log, D, ybf, h0b, cdec, Cp);
    k3b_chunkscan<<<128, 256, 0, stream>>>(h0b, cdec);
    k4_out<<<512, 256, 0, stream>>>(ybf, norm_gate, out_proj_w, in_proj_w, block_norm, x, h0b, cdec, Cp, out);
}